// Round 17
// baseline (54.730 us; speedup 1.0000x reference)
//
#include <hip/hip_runtime.h>

#define NFEAT   100000
#define NBATCH  256
#define DIM     128
#define MARGIN_F 0.5f
#define FLT_BIG 3.402823466e+38f

// ---- bf16-path geometry (K1b): 625 blocks x 160 rows = 100000 exactly
#define GRIDB   625
#define RPBB    160
#define NTILEB  10                        // 16-row compute tiles per block
#define BBYTESB (RPBB * DIM * 2)          // 40 KiB bf16 staged per block
#define STAGEIT (BBYTESB / (512 * 16))    // 5 staging iterations (512 thr x 16B)

// ---- f32 fallback geometry (R13): 1250 x 80
#define GRIDF   1250
#define RPBF    80
#define NTILEF  5

typedef __bf16 bf8_t  __attribute__((ext_vector_type(8)));
typedef short  sh8_t  __attribute__((ext_vector_type(8)));
typedef float  f32x4  __attribute__((ext_vector_type(4)));

// f32 -> bf16 native cast: compiler emits v_cvt_pk_bf16_f32 pairs (RTNE).
__device__ __forceinline__ bf8_t pack8(float4 v0, float4 v1) {
  bf8_t r;
  r[0] = (__bf16)v0.x; r[1] = (__bf16)v0.y; r[2] = (__bf16)v0.z; r[3] = (__bf16)v0.w;
  r[4] = (__bf16)v1.x; r[5] = (__bf16)v1.y; r[6] = (__bf16)v1.z; r[7] = (__bf16)v1.w;
  return r;
}

// MFMA dispatch: works whether the builtin takes bf16-vectors or short-vectors
template <typename VA, typename VC>
__device__ __forceinline__ auto mfma_sel(VA a, VA b, VC c, int)
    -> decltype(__builtin_amdgcn_mfma_f32_16x16x32_bf16(a, b, c, 0, 0, 0)) {
  return __builtin_amdgcn_mfma_f32_16x16x32_bf16(a, b, c, 0, 0, 0);
}
template <typename VA, typename VC>
__device__ __forceinline__ VC mfma_sel(VA a, VA b, VC c, long) {
  return __builtin_amdgcn_mfma_f32_16x16x32_bf16(
      __builtin_bit_cast(sh8_t, a), __builtin_bit_cast(sh8_t, b), c, 0, 0, 0);
}
__device__ __forceinline__ f32x4 mfma_bf16(bf8_t a, bf8_t b, f32x4 c) {
  return mfma_sel(a, b, c, 0);
}

#if defined(__has_builtin)
#if __has_builtin(__builtin_amdgcn_global_load_lds)
#define HAVE_GLLDS 1
#endif
#endif

__device__ __forceinline__ void stage16(const char* g, char* l) {
#ifdef HAVE_GLLDS
  __builtin_amdgcn_global_load_lds(
      (const __attribute__((address_space(1))) unsigned int*)g,
      (__attribute__((address_space(3))) unsigned int*)l, 16, 0, 0);
#else
  *reinterpret_cast<float4*>(l) = *reinterpret_cast<const float4*>(g);
#endif
}

#define CFENCE()  asm volatile("" ::: "memory")

// ============================================================================
// K1a: streaming f32->bf16 cast of features into d_ws. Measured R16: ~8us for
// 77 MB (~9 TB/s) -- the plain-load path in this environment is healthy; the
// slow GEMM blocks are structural, not environmental.
// ============================================================================
__global__ __launch_bounds__(256) void feat_to_bf16(
    const float* __restrict__ src, __bf16* __restrict__ dst,
    float* __restrict__ out)
{
  if (blockIdx.x == 0 && threadIdx.x == 0) out[0] = 0.0f;  // K2 accumulates
  const int gid    = blockIdx.x * 256 + threadIdx.x;
  const int stride = gridDim.x * 256;
  const int n8     = NFEAT * DIM / 8;     // 1.6M groups of 8 elems
  for (int i = gid; i < n8; i += stride) {
    const float* p = src + (size_t)i * 8;
    float4 v0 = *reinterpret_cast<const float4*>(p);
    float4 v1 = *reinterpret_cast<const float4*>(p + 4);
    *reinterpret_cast<bf8_t*>(dst + (size_t)i * 8) = pack8(v0, v1);
  }
}

// ============================================================================
// K1b: fused GEMM + masked min/max partials, BF16 features from d_ws.
// Burst-stage barrier-once. R17 fixes:
//  (1) BUG: staging loop ran NTILEB(=10) iters = 80 KB into a 40 KB buffer
//      (OOB LDS writes HW-dropped -> passed silently; OOB global reads on the
//      last block; 2x DMA instructions). Correct count = STAGEIT = 5.
//      R13/R15/R16-bug all issued exactly 50K wave-DMA insts and took
//      42-54us (~600cyc/inst/CU): this halves the count -> direct law test.
//  (2) A/meta/label loads issued BEFORE the DMA burst: vmcnt retires in
//      order, so with DMAs first, consuming A drains the whole queue; with
//      A first, the A-conversion overlaps DMA flight.
// 625 blocks x 512 thr (8 waves x 2 M-tiles); 40 KiB LDS; swizzle
// byte ^= (row&7)<<4 within 256B bf16 rows via pre-swizzled DMA source
// (linear LDS dest, rule 21), undone on read. Partials [blk][row] contiguous
// (R13: transposed = cross-XCD ping-pong). (512,2) cap (R6: tighter = spills).
// MFMA 16x16x32 layouts (guide §3, m89/m91-verified).
// ============================================================================
__global__ __launch_bounds__(512, 2) void triplet_partial_bf16(
    const float* __restrict__ inputs, const __bf16* __restrict__ featb,
    const int* __restrict__ targets, const int* __restrict__ flabels,
    const int* __restrict__ idx,
    float* __restrict__ ppos, float* __restrict__ pneg)
{
  __shared__ char sB[BBYTESB];         // 40 KiB bf16: 160 rows x 256B

  const int tid  = threadIdx.x;
  const int lane = tid & 63;
  const int wv   = tid >> 6;      // 0..7
  const int l15  = lane & 15;
  const int lg   = lane >> 4;     // 0..3
  const int m0   = wv * 32;
  const int blk  = blockIdx.x;
  const int rowbase = blk * RPBB;

  // ---- 1) A loads first (oldest in vmcnt queue: consumable without
  // draining the younger stage DMAs).
  float4 av0[2][4], av1[2][4];
#pragma unroll
  for (int mt = 0; mt < 2; ++mt) {
    const float* ap = inputs + (m0 + mt * 16 + l15) * DIM;
#pragma unroll
    for (int ks = 0; ks < 4; ++ks) {
      const int k = ks * 32 + lg * 8;
      av0[mt][ks] = *reinterpret_cast<const float4*>(ap + k);
      av1[mt][ks] = *reinterpret_cast<const float4*>(ap + k + 4);
    }
  }
  // labels + meta loads (scalar-ish, still older than the DMAs)
  int lab[NTILEB];
#pragma unroll
  for (int t = 0; t < NTILEB; ++t)
    lab[t] = flabels[rowbase + t * 16 + l15];
  int mrow[2][4], mlab[2][4];
#pragma unroll
  for (int mt = 0; mt < 2; ++mt)
#pragma unroll
    for (int rr = 0; rr < 4; ++rr) {
      const int row = m0 + mt * 16 + lg * 4 + rr;
      mrow[mt][rr] = idx[row];
      mlab[mt][rr] = targets[row];
    }
  CFENCE();

  // ---- 2) burst-stage ALL 40 KiB of B (exactly STAGEIT=5 x 16B per thread),
  // linear LDS dest, pre-swizzled global source (256B bf16 rows).
#pragma unroll
  for (int i = 0; i < STAGEIT; ++i) {
    const int p    = i * 8192 + tid * 16;     // LDS byte offset, < 40960
    const int prow = p >> 8;                  // 0..159
    const int scol = (p & 255) ^ ((prow & 7) << 4);
    stage16((const char*)featb + (size_t)(rowbase + prow) * 256 + scol,
            &sB[p]);
  }
  CFENCE();

  // ---- 3) convert A + pack meta while the DMAs fly (waits only groups 1)
  bf8_t afrag[2][4];
#pragma unroll
  for (int mt = 0; mt < 2; ++mt)
#pragma unroll
    for (int ks = 0; ks < 4; ++ks)
      afrag[mt][ks] = pack8(av0[mt][ks], av1[mt][ks]);
  int meta[2][4];
#pragma unroll
  for (int mt = 0; mt < 2; ++mt)
#pragma unroll
    for (int rr = 0; rr < 4; ++rr)
      meta[mt][rr] = (mrow[mt][rr] << 10) | mlab[mt][rr];   // lab<1000: 10 bits

  float minpos[2][4], maxneg[2][4];
#pragma unroll
  for (int mt = 0; mt < 2; ++mt)
#pragma unroll
    for (int rr = 0; rr < 4; ++rr) { minpos[mt][rr] = FLT_BIG; maxneg[mt][rr] = -FLT_BIG; }

  __syncthreads();   // the ONE drain: all DMAs landed, B fully in LDS

  // ---- 4) barrier-free compute: 10 tiles from LDS, bfrag = raw ds_read_b128
  const int swz = (l15 & 7) << 4;
#pragma unroll
  for (int t = 0; t < NTILEB; ++t) {
    const char* rbase = &sB[(t * 16 + l15) * 256];
    const int   j     = rowbase + t * 16 + l15;
    const int   labj  = lab[t];

    f32x4 acc0 = {0.f, 0.f, 0.f, 0.f};
    f32x4 acc1 = {0.f, 0.f, 0.f, 0.f};
#pragma unroll
    for (int ks = 0; ks < 4; ++ks) {
      const int o = (ks * 64 + lg * 16) ^ swz;
      bf8_t bf = *reinterpret_cast<const bf8_t*>(rbase + o);
      acc0 = mfma_bf16(afrag[0][ks], bf, acc0);
      acc1 = mfma_bf16(afrag[1][ks], bf, acc1);
    }

#pragma unroll
    for (int rr = 0; rr < 4; ++rr) {
      {
        const int   m    = meta[0][rr];
        const bool same  = (labj == (m & 1023));
        const bool self  = (j == (m >> 10));
        minpos[0][rr] = fminf(minpos[0][rr], (same && !self) ? acc0[rr] : FLT_BIG);
        maxneg[0][rr] = fmaxf(maxneg[0][rr], same ? -FLT_BIG : acc0[rr]);
      }
      {
        const int   m    = meta[1][rr];
        const bool same  = (labj == (m & 1023));
        const bool self  = (j == (m >> 10));
        minpos[1][rr] = fminf(minpos[1][rr], (same && !self) ? acc1[rr] : FLT_BIG);
        maxneg[1][rr] = fmaxf(maxneg[1][rr], same ? -FLT_BIG : acc1[rr]);
      }
    }
  }

  // ---- 5) reduce across the 16-lane col group; contiguous [blk][row] write
#pragma unroll
  for (int mt = 0; mt < 2; ++mt)
#pragma unroll
    for (int rr = 0; rr < 4; ++rr) {
      float mp = minpos[mt][rr], mn = maxneg[mt][rr];
#pragma unroll
      for (int m = 1; m < 16; m <<= 1) {
        mp = fminf(mp, __shfl_xor(mp, m, 64));
        mn = fmaxf(mn, __shfl_xor(mn, m, 64));
      }
      if (l15 == 0) {
        const int row = m0 + mt * 16 + lg * 4 + rr;
        ppos[blk * NBATCH + row] = mp;
        pneg[blk * NBATCH + row] = mn;
      }
    }
}

// ============================================================================
// Fallback (ws too small): R13 f32 monolith, 1250 x 80, known-good ~43us path.
// ============================================================================
__global__ __launch_bounds__(512, 2) void triplet_partial_f32(
    const float* __restrict__ inputs, const float* __restrict__ features,
    const int* __restrict__ targets, const int* __restrict__ flabels,
    const int* __restrict__ idx,
    float* __restrict__ ppos, float* __restrict__ pneg,
    float* __restrict__ out)
{
  __shared__ char sB[RPBF * DIM * 4];

  const int tid  = threadIdx.x;
  const int lane = tid & 63;
  const int wv   = tid >> 6;
  const int l15  = lane & 15;
  const int lg   = lane >> 4;
  const int m0   = wv * 32;
  const int blk  = blockIdx.x;
  const int rowbase = blk * RPBF;

  if (blk == 0 && tid == 0) out[0] = 0.0f;

#pragma unroll
  for (int i = 0; i < NTILEF; ++i) {
    const int p    = i * 8192 + tid * 16;
    const int prow = p >> 9;
    const int scol = (p & 511) ^ ((prow & 7) << 4);
    stage16((const char*)features + (size_t)(rowbase + prow) * 512 + scol, &sB[p]);
  }

  bf8_t afrag[2][4];
#pragma unroll
  for (int mt = 0; mt < 2; ++mt) {
    const float* ap = inputs + (m0 + mt * 16 + l15) * DIM;
    float4 v0[4], v1[4];
#pragma unroll
    for (int ks = 0; ks < 4; ++ks) {
      const int k = ks * 32 + lg * 8;
      v0[ks] = *reinterpret_cast<const float4*>(ap + k);
      v1[ks] = *reinterpret_cast<const float4*>(ap + k + 4);
    }
#pragma unroll
    for (int ks = 0; ks < 4; ++ks)
      afrag[mt][ks] = pack8(v0[ks], v1[ks]);
  }

  int lab[NTILEF];
#pragma unroll
  for (int t = 0; t < NTILEF; ++t)
    lab[t] = flabels[rowbase + t * 16 + l15];

  int meta[2][4];
#pragma unroll
  for (int mt = 0; mt < 2; ++mt)
#pragma unroll
    for (int rr = 0; rr < 4; ++rr) {
      const int row = m0 + mt * 16 + lg * 4 + rr;
      meta[mt][rr] = (idx[row] << 10) | targets[row];
    }

  float minpos[2][4], maxneg[2][4];
#pragma unroll
  for (int mt = 0; mt < 2; ++mt)
#pragma unroll
    for (int rr = 0; rr < 4; ++rr) { minpos[mt][rr] = FLT_BIG; maxneg[mt][rr] = -FLT_BIG; }

  __syncthreads();

  const int swz = (l15 & 7) << 4;
#pragma unroll
  for (int t = 0; t < NTILEF; ++t) {
    const char* rbase = &sB[(t * 16 + l15) * 512];
    const int   j     = rowbase + t * 16 + l15;
    const int   labj  = lab[t];

    f32x4 acc0 = {0.f, 0.f, 0.f, 0.f};
    f32x4 acc1 = {0.f, 0.f, 0.f, 0.f};
#pragma unroll
    for (int ks = 0; ks < 4; ++ks) {
      const int o = ks * 128 + lg * 32;
      float4 v0 = *reinterpret_cast<const float4*>(rbase + ((o)      ^ swz));
      float4 v1 = *reinterpret_cast<const float4*>(rbase + ((o + 16) ^ swz));
      bf8_t bf = pack8(v0, v1);
      acc0 = mfma_bf16(afrag[0][ks], bf, acc0);
      acc1 = mfma_bf16(afrag[1][ks], bf, acc1);
    }
#pragma unroll
    for (int rr = 0; rr < 4; ++rr) {
      {
        const int  m = meta[0][rr];
        const bool same = (labj == (m & 1023));
        const bool self = (j == (m >> 10));
        minpos[0][rr] = fminf(minpos[0][rr], (same && !self) ? acc0[rr] : FLT_BIG);
        maxneg[0][rr] = fmaxf(maxneg[0][rr], same ? -FLT_BIG : acc0[rr]);
      }
      {
        const int  m = meta[1][rr];
        const bool same = (labj == (m & 1023));
        const bool self = (j == (m >> 10));
        minpos[1][rr] = fminf(minpos[1][rr], (same && !self) ? acc1[rr] : FLT_BIG);
        maxneg[1][rr] = fmaxf(maxneg[1][rr], same ? -FLT_BIG : acc1[rr]);
      }
    }
  }

#pragma unroll
  for (int mt = 0; mt < 2; ++mt)
#pragma unroll
    for (int rr = 0; rr < 4; ++rr) {
      float mp = minpos[mt][rr], mn = maxneg[mt][rr];
#pragma unroll
      for (int m = 1; m < 16; m <<= 1) {
        mp = fminf(mp, __shfl_xor(mp, m, 64));
        mn = fmaxf(mn, __shfl_xor(mn, m, 64));
      }
      if (l15 == 0) {
        const int row = m0 + mt * 16 + lg * 4 + rr;
        ppos[blk * NBATCH + row] = mp;
        pneg[blk * NBATCH + row] = mn;
      }
    }
}

// Kernel 2: one block per batch row; fold nblk partials, hinge, atomic mean.
__global__ __launch_bounds__(256) void triplet_reduce(
    const float* __restrict__ ppos, const float* __restrict__ pneg,
    float* __restrict__ out, int nblk)
{
  const int r = blockIdx.x;
  const int t = threadIdx.x;
  float mp = FLT_BIG, mn = -FLT_BIG;
  for (int b = t; b < nblk; b += 256) {
    mp = fminf(mp, ppos[b * NBATCH + r]);
    mn = fmaxf(mn, pneg[b * NBATCH + r]);
  }
#pragma unroll
  for (int m = 1; m < 64; m <<= 1) {
    mp = fminf(mp, __shfl_xor(mp, m, 64));
    mn = fmaxf(mn, __shfl_xor(mn, m, 64));
  }
  __shared__ float smp[4], smn[4];
  if ((t & 63) == 0) { smp[t >> 6] = mp; smn[t >> 6] = mn; }
  __syncthreads();
  if (t == 0) {
    mp = fminf(fminf(smp[0], smp[1]), fminf(smp[2], smp[3]));
    mn = fmaxf(fmaxf(smn[0], smn[1]), fmaxf(smn[2], smn[3]));
    float loss = mn - mp + MARGIN_F;
    loss = loss > 0.f ? loss : 0.f;
    atomicAdd(out, loss * (1.0f / NBATCH));
  }
}

extern "C" void kernel_launch(void* const* d_in, const int* in_sizes, int n_in,
                              void* d_out, int out_size, void* d_ws, size_t ws_size,
                              hipStream_t stream) {
  const float* inputs   = (const float*)d_in[0];
  const float* features = (const float*)d_in[1];
  const int*   targets  = (const int*)d_in[2];
  const int*   flabels  = (const int*)d_in[3];
  const int*   idx      = (const int*)d_in[4];
  float* out = (float*)d_out;

  const size_t featb_bytes = (size_t)NFEAT * DIM * 2;           // 25.6 MB
  const size_t part_bytes  = (size_t)GRIDB * NBATCH * 4;        // 640 KB each

  if (ws_size >= featb_bytes + 2 * part_bytes) {
    __bf16* featb = (__bf16*)d_ws;
    float*  ppos  = (float*)((char*)d_ws + featb_bytes);
    float*  pneg  = ppos + (size_t)GRIDB * NBATCH;
    feat_to_bf16<<<2048, 256, 0, stream>>>(features, featb, out);
    triplet_partial_bf16<<<GRIDB, 512, 0, stream>>>(inputs, featb, targets,
                                                    flabels, idx, ppos, pneg);
    triplet_reduce<<<NBATCH, 256, 0, stream>>>(ppos, pneg, out, GRIDB);
  } else {
    float* ppos = (float*)d_ws;                       // [GRIDF][256]
    float* pneg = ppos + (size_t)GRIDF * NBATCH;      // ~2.56 MB total
    triplet_partial_f32<<<GRIDF, 512, 0, stream>>>(inputs, features, targets,
                                                   flabels, idx, ppos, pneg, out);
    triplet_reduce<<<NBATCH, 256, 0, stream>>>(ppos, pneg, out, GRIDF);
  }
}

// Round 18
// 42.525 us; speedup vs baseline: 1.2870x; 1.2870x over previous
//
#include <hip/hip_runtime.h>

#define NFEAT   100000
#define NBATCH  256
#define DIM     128
#define MARGIN_F 0.5f
#define FLT_BIG 3.402823466e+38f

// ---- main geometry: 250 blocks x 400 rows = 100000 exactly; 25 chunks of 16
#define GRID    250
#define CHUNKS  25
#define CROWS   16
#define RPB     (CHUNKS * CROWS)          // 400
#define CBYTES  (CROWS * DIM * 2)         // 4 KiB bf16 per chunk

// ---- f32 fallback geometry (R13): 1250 x 80
#define GRIDF   1250
#define RPBF    80
#define NTILEF  5

typedef __bf16 bf8_t  __attribute__((ext_vector_type(8)));
typedef short  sh8_t  __attribute__((ext_vector_type(8)));
typedef float  f32x4  __attribute__((ext_vector_type(4)));

__device__ __forceinline__ bf8_t pack8(float4 v0, float4 v1) {
  bf8_t r;
  r[0] = (__bf16)v0.x; r[1] = (__bf16)v0.y; r[2] = (__bf16)v0.z; r[3] = (__bf16)v0.w;
  r[4] = (__bf16)v1.x; r[5] = (__bf16)v1.y; r[6] = (__bf16)v1.z; r[7] = (__bf16)v1.w;
  return r;
}

template <typename VA, typename VC>
__device__ __forceinline__ auto mfma_sel(VA a, VA b, VC c, int)
    -> decltype(__builtin_amdgcn_mfma_f32_16x16x32_bf16(a, b, c, 0, 0, 0)) {
  return __builtin_amdgcn_mfma_f32_16x16x32_bf16(a, b, c, 0, 0, 0);
}
template <typename VA, typename VC>
__device__ __forceinline__ VC mfma_sel(VA a, VA b, VC c, long) {
  return __builtin_amdgcn_mfma_f32_16x16x32_bf16(
      __builtin_bit_cast(sh8_t, a), __builtin_bit_cast(sh8_t, b), c, 0, 0, 0);
}
__device__ __forceinline__ f32x4 mfma_bf16(bf8_t a, bf8_t b, f32x4 c) {
  return mfma_sel(a, b, c, 0);
}

#if defined(__has_builtin)
#if __has_builtin(__builtin_amdgcn_global_load_lds)
#define HAVE_GLLDS 1
#endif
#endif

__device__ __forceinline__ void stage16(const char* g, char* l) {
#ifdef HAVE_GLLDS
  __builtin_amdgcn_global_load_lds(
      (const __attribute__((address_space(1))) unsigned int*)g,
      (__attribute__((address_space(3))) unsigned int*)l, 16, 0, 0);
#else
  *reinterpret_cast<float4*>(l) = *reinterpret_cast<const float4*>(g);
#endif
}

#define CFENCE()  asm volatile("" ::: "memory")
#define LGKM0()   asm volatile("s_waitcnt lgkmcnt(0)" ::: "memory")

// ============================================================================
// K1a: streaming f32->bf16 cast of inputs (64 KB) + features (25.6 MB) into
// d_ws. Measured R16/17: ~8us (~9 TB/s) -- the plain-load stream is healthy.
// ============================================================================
#define NG_IN   (NBATCH * DIM / 8)        // 4096 groups
#define NG_ALL  (NG_IN + NFEAT * DIM / 8) // 4096 + 1.6M
__global__ __launch_bounds__(256) void cast_bf16(
    const float* __restrict__ inputs, const float* __restrict__ features,
    __bf16* __restrict__ inb, __bf16* __restrict__ featb,
    float* __restrict__ out)
{
  if (blockIdx.x == 0 && threadIdx.x == 0) out[0] = 0.0f;  // K2 accumulates
  const int gid    = blockIdx.x * 256 + threadIdx.x;
  const int stride = gridDim.x * 256;
  for (int i = gid; i < NG_ALL; i += stride) {
    const float* src; __bf16* dst;
    if (i < NG_IN) { src = inputs + (size_t)i * 8;           dst = inb   + (size_t)i * 8; }
    else           { src = features + (size_t)(i - NG_IN) * 8; dst = featb + (size_t)(i - NG_IN) * 8; }
    float4 v0 = *reinterpret_cast<const float4*>(src);
    float4 v1 = *reinterpret_cast<const float4*>(src + 4);
    *reinterpret_cast<bf8_t*>(dst) = pack8(v0, v1);
  }
}

// ============================================================================
// K1b (R18): ONE BLOCK PER CU, A LOADED ONCE, CONTINUOUS STREAM.
// Diagnosis R17: per-CU delivered load BW was 9 GB/s/CU vs K1a's healthy 25 --
// two multiplicative causes: (1) per-block A-reload (625x128KB = 80 MB, 3x the
// feature stream) re-paid every block generation; (2) bursty load duty cycle.
// Fix: 250 blocks x 400 rows (= 100000), 1 block/CU, A read ONCE as bf16
// frags (no cvt), 25 chunks of 16 rows streamed via depth-4 rotating reg
// prefetch (8B/thread/chunk) -> loads issue EVERY iteration (continuous),
// ds_write waits only its own reg (counted vmcnt by construction), LDS 2x4KB
// double buffer, one barrier per chunk amortized over 25 iters.
// Total vector-load traffic: 25.6 MB featb + 16 MB A = 42 MB (vs ~106 MB).
// Swizzle on ds_write ADDRESS (reg-staged; global reads linear); reads undo
// (byte ^= (row&7)<<4). Partials [blk][row] contiguous (R13). (512,2) cap.
// MFMA 16x16x32 layouts (guide §3, m89/m91-verified):
//   A: lane l holds A[m0 + (l&15)][k0 + (l>>4)*8 + e]
//   B: lane l holds B[k0 + (l>>4)*8 + e][j0 + (l&15)]   (= features[j][k])
//   D: lane l reg r = sim[m0 + (l>>4)*4 + r][j0 + (l&15)]
// ============================================================================
__global__ __launch_bounds__(512, 2) void triplet_main(
    const __bf16* __restrict__ inb, const __bf16* __restrict__ featb,
    const int* __restrict__ targets, const int* __restrict__ flabels,
    const int* __restrict__ idx,
    float* __restrict__ ppos, float* __restrict__ pneg)
{
  __shared__ char sB[2][CBYTES];       // 8 KiB double buffer
  __shared__ int  slab[RPB];           // labels for this block's 400 rows

  const int tid  = threadIdx.x;
  const int lane = tid & 63;
  const int wv   = tid >> 6;      // 0..7
  const int l15  = lane & 15;
  const int lg   = lane >> 4;     // 0..3
  const int m0   = wv * 32;
  const int blk  = blockIdx.x;
  const int rowbase = blk * RPB;

  // ---- A fragments: direct bf16 loads, ONCE per block (no conversion).
  bf8_t afrag[2][4];
#pragma unroll
  for (int mt = 0; mt < 2; ++mt)
#pragma unroll
    for (int ks = 0; ks < 4; ++ks)
      afrag[mt][ks] = *reinterpret_cast<const bf8_t*>(
          (const char*)inb + (size_t)(m0 + mt * 16 + l15) * 256 + ks * 64 + lg * 16);

  // meta + labels
  int meta[2][4];
#pragma unroll
  for (int mt = 0; mt < 2; ++mt)
#pragma unroll
    for (int rr = 0; rr < 4; ++rr) {
      const int row = m0 + mt * 16 + lg * 4 + rr;
      meta[mt][rr] = (idx[row] << 10) | targets[row];   // lab<1000: 10 bits
    }
  int labv = 0;
  if (tid < RPB) labv = flabels[rowbase + tid];

  // ---- rotating depth-4 prefetch: thread tid owns 8B of each 4KB chunk
  const char* gsrc = (const char*)featb + (size_t)rowbase * 256 + tid * 8;
  const int p    = tid * 8;
  const int prow = p >> 8;                         // 0..15
  const int pd   = p ^ ((prow & 7) << 4);          // swizzled LDS byte offset

  ushort4 rbuf[4];
  rbuf[0] = *reinterpret_cast<const ushort4*>(gsrc + 0 * CBYTES);
  rbuf[1] = *reinterpret_cast<const ushort4*>(gsrc + 1 * CBYTES);
  rbuf[2] = *reinterpret_cast<const ushort4*>(gsrc + 2 * CBYTES);
  rbuf[3] = *reinterpret_cast<const ushort4*>(gsrc + 3 * CBYTES);
  CFENCE();

  float minpos[2][4], maxneg[2][4];
#pragma unroll
  for (int mt = 0; mt < 2; ++mt)
#pragma unroll
    for (int rr = 0; rr < 4; ++rr) { minpos[mt][rr] = FLT_BIG; maxneg[mt][rr] = -FLT_BIG; }

  // LDS prologue: labels + chunk 0 (ds_write waits only rbuf[0]'s load)
  if (tid < RPB) slab[tid] = labv;
  *reinterpret_cast<ushort4*>(&sB[0][pd]) = rbuf[0];
  LGKM0();
  __builtin_amdgcn_s_barrier();
  CFENCE();

  // ---- main loop: load c+4 | compute c | write c+1 | barrier
  const int swz = (l15 & 7) << 4;
#pragma unroll
  for (int c = 0; c < CHUNKS; ++c) {
    // 1) issue next prefetch (slot (c+4)&3 == c&3: chunk c was written to LDS
    //    at iter c-1 and its ds_write drained by that iter's lgkmcnt(0)).
    if (c + 4 < CHUNKS)
      rbuf[c & 3] = *reinterpret_cast<const ushort4*>(gsrc + (size_t)(c + 4) * CBYTES);

    // 2) compute chunk c from sB[c&1]
    const char* rb  = &sB[c & 1][l15 * 256];
    const int  j    = rowbase + c * CROWS + l15;
    const int  labj = slab[c * CROWS + l15];

    f32x4 acc0 = {0.f, 0.f, 0.f, 0.f};
    f32x4 acc1 = {0.f, 0.f, 0.f, 0.f};
#pragma unroll
    for (int ks = 0; ks < 4; ++ks) {
      bf8_t bf = *reinterpret_cast<const bf8_t*>(rb + ((ks * 64 + lg * 16) ^ swz));
      acc0 = mfma_bf16(afrag[0][ks], bf, acc0);
      acc1 = mfma_bf16(afrag[1][ks], bf, acc1);
    }
#pragma unroll
    for (int rr = 0; rr < 4; ++rr) {
      {
        const int  m    = meta[0][rr];
        const bool same = (labj == (m & 1023));
        const bool self = (j == (m >> 10));
        minpos[0][rr] = fminf(minpos[0][rr], (same && !self) ? acc0[rr] : FLT_BIG);
        maxneg[0][rr] = fmaxf(maxneg[0][rr], same ? -FLT_BIG : acc0[rr]);
      }
      {
        const int  m    = meta[1][rr];
        const bool same = (labj == (m & 1023));
        const bool self = (j == (m >> 10));
        minpos[1][rr] = fminf(minpos[1][rr], (same && !self) ? acc1[rr] : FLT_BIG);
        maxneg[1][rr] = fmaxf(maxneg[1][rr], same ? -FLT_BIG : acc1[rr]);
      }
    }

    // 3) stage chunk c+1 into the buffer computed two chunks ago (barrier-
    //    protected). ds_write waits ONLY rbuf[(c+1)&3] (loaded at c-3).
    if (c + 1 < CHUNKS)
      *reinterpret_cast<ushort4*>(&sB[(c + 1) & 1][pd]) = rbuf[(c + 1) & 3];

    // 4) my ds_write visible; block rendezvous. vmcnt prefetches stay in flight.
    LGKM0();
    __builtin_amdgcn_s_barrier();
    CFENCE();
  }

  // ---- reduce across the 16-lane col group; contiguous [blk][row] writes
#pragma unroll
  for (int mt = 0; mt < 2; ++mt)
#pragma unroll
    for (int rr = 0; rr < 4; ++rr) {
      float mp = minpos[mt][rr], mn = maxneg[mt][rr];
#pragma unroll
      for (int m = 1; m < 16; m <<= 1) {
        mp = fminf(mp, __shfl_xor(mp, m, 64));
        mn = fmaxf(mn, __shfl_xor(mn, m, 64));
      }
      if (l15 == 0) {
        const int row = m0 + mt * 16 + lg * 4 + rr;
        ppos[blk * NBATCH + row] = mp;
        pneg[blk * NBATCH + row] = mn;
      }
    }
}

// ============================================================================
// Fallback (ws too small): R13 f32 monolith, known-good ~43us path.
// ============================================================================
__global__ __launch_bounds__(512, 2) void triplet_partial_f32(
    const float* __restrict__ inputs, const float* __restrict__ features,
    const int* __restrict__ targets, const int* __restrict__ flabels,
    const int* __restrict__ idx,
    float* __restrict__ ppos, float* __restrict__ pneg,
    float* __restrict__ out)
{
  __shared__ char sB[RPBF * DIM * 4];

  const int tid  = threadIdx.x;
  const int lane = tid & 63;
  const int wv   = tid >> 6;
  const int l15  = lane & 15;
  const int lg   = lane >> 4;
  const int m0   = wv * 32;
  const int blk  = blockIdx.x;
  const int rowbase = blk * RPBF;

  if (blk == 0 && tid == 0) out[0] = 0.0f;

#pragma unroll
  for (int i = 0; i < NTILEF; ++i) {
    const int p    = i * 8192 + tid * 16;
    const int prow = p >> 9;
    const int scol = (p & 511) ^ ((prow & 7) << 4);
    stage16((const char*)features + (size_t)(rowbase + prow) * 512 + scol, &sB[p]);
  }

  bf8_t afrag[2][4];
#pragma unroll
  for (int mt = 0; mt < 2; ++mt) {
    const float* ap = inputs + (m0 + mt * 16 + l15) * DIM;
    float4 v0[4], v1[4];
#pragma unroll
    for (int ks = 0; ks < 4; ++ks) {
      const int k = ks * 32 + lg * 8;
      v0[ks] = *reinterpret_cast<const float4*>(ap + k);
      v1[ks] = *reinterpret_cast<const float4*>(ap + k + 4);
    }
#pragma unroll
    for (int ks = 0; ks < 4; ++ks)
      afrag[mt][ks] = pack8(v0[ks], v1[ks]);
  }

  int lab[NTILEF];
#pragma unroll
  for (int t = 0; t < NTILEF; ++t)
    lab[t] = flabels[rowbase + t * 16 + l15];

  int meta[2][4];
#pragma unroll
  for (int mt = 0; mt < 2; ++mt)
#pragma unroll
    for (int rr = 0; rr < 4; ++rr) {
      const int row = m0 + mt * 16 + lg * 4 + rr;
      meta[mt][rr] = (idx[row] << 10) | targets[row];
    }

  float minpos[2][4], maxneg[2][4];
#pragma unroll
  for (int mt = 0; mt < 2; ++mt)
#pragma unroll
    for (int rr = 0; rr < 4; ++rr) { minpos[mt][rr] = FLT_BIG; maxneg[mt][rr] = -FLT_BIG; }

  __syncthreads();

  const int swz = (l15 & 7) << 4;
#pragma unroll
  for (int t = 0; t < NTILEF; ++t) {
    const char* rbase = &sB[(t * 16 + l15) * 512];
    const int   j     = rowbase + t * 16 + l15;
    const int   labj  = lab[t];

    f32x4 acc0 = {0.f, 0.f, 0.f, 0.f};
    f32x4 acc1 = {0.f, 0.f, 0.f, 0.f};
#pragma unroll
    for (int ks = 0; ks < 4; ++ks) {
      const int o = ks * 128 + lg * 32;
      float4 v0 = *reinterpret_cast<const float4*>(rbase + ((o)      ^ swz));
      float4 v1 = *reinterpret_cast<const float4*>(rbase + ((o + 16) ^ swz));
      bf8_t bf = pack8(v0, v1);
      acc0 = mfma_bf16(afrag[0][ks], bf, acc0);
      acc1 = mfma_bf16(afrag[1][ks], bf, acc1);
    }
#pragma unroll
    for (int rr = 0; rr < 4; ++rr) {
      {
        const int  m = meta[0][rr];
        const bool same = (labj == (m & 1023));
        const bool self = (j == (m >> 10));
        minpos[0][rr] = fminf(minpos[0][rr], (same && !self) ? acc0[rr] : FLT_BIG);
        maxneg[0][rr] = fmaxf(maxneg[0][rr], same ? -FLT_BIG : acc0[rr]);
      }
      {
        const int  m = meta[1][rr];
        const bool same = (labj == (m & 1023));
        const bool self = (j == (m >> 10));
        minpos[1][rr] = fminf(minpos[1][rr], (same && !self) ? acc1[rr] : FLT_BIG);
        maxneg[1][rr] = fmaxf(maxneg[1][rr], same ? -FLT_BIG : acc1[rr]);
      }
    }
  }

#pragma unroll
  for (int mt = 0; mt < 2; ++mt)
#pragma unroll
    for (int rr = 0; rr < 4; ++rr) {
      float mp = minpos[mt][rr], mn = maxneg[mt][rr];
#pragma unroll
      for (int m = 1; m < 16; m <<= 1) {
        mp = fminf(mp, __shfl_xor(mp, m, 64));
        mn = fmaxf(mn, __shfl_xor(mn, m, 64));
      }
      if (l15 == 0) {
        const int row = m0 + mt * 16 + lg * 4 + rr;
        ppos[blk * NBATCH + row] = mp;
        pneg[blk * NBATCH + row] = mn;
      }
    }
}

// Kernel 2: one block per batch row; fold nblk partials, hinge, atomic mean.
__global__ __launch_bounds__(256) void triplet_reduce(
    const float* __restrict__ ppos, const float* __restrict__ pneg,
    float* __restrict__ out, int nblk)
{
  const int r = blockIdx.x;
  const int t = threadIdx.x;
  float mp = FLT_BIG, mn = -FLT_BIG;
  for (int b = t; b < nblk; b += 256) {
    mp = fminf(mp, ppos[b * NBATCH + r]);
    mn = fmaxf(mn, pneg[b * NBATCH + r]);
  }
#pragma unroll
  for (int m = 1; m < 64; m <<= 1) {
    mp = fminf(mp, __shfl_xor(mp, m, 64));
    mn = fmaxf(mn, __shfl_xor(mn, m, 64));
  }
  __shared__ float smp[4], smn[4];
  if ((t & 63) == 0) { smp[t >> 6] = mp; smn[t >> 6] = mn; }
  __syncthreads();
  if (t == 0) {
    mp = fminf(fminf(smp[0], smp[1]), fminf(smp[2], smp[3]));
    mn = fmaxf(fmaxf(smn[0], smn[1]), fmaxf(smn[2], smn[3]));
    float loss = mn - mp + MARGIN_F;
    loss = loss > 0.f ? loss : 0.f;
    atomicAdd(out, loss * (1.0f / NBATCH));
  }
}

extern "C" void kernel_launch(void* const* d_in, const int* in_sizes, int n_in,
                              void* d_out, int out_size, void* d_ws, size_t ws_size,
                              hipStream_t stream) {
  const float* inputs   = (const float*)d_in[0];
  const float* features = (const float*)d_in[1];
  const int*   targets  = (const int*)d_in[2];
  const int*   flabels  = (const int*)d_in[3];
  const int*   idx      = (const int*)d_in[4];
  float* out = (float*)d_out;

  const size_t featb_bytes = (size_t)NFEAT * DIM * 2;    // 25.6 MB
  const size_t inb_bytes   = (size_t)NBATCH * DIM * 2;   // 64 KB
  const size_t part_bytes  = (size_t)GRID * NBATCH * 4;  // 256 KB each

  if (ws_size >= featb_bytes + inb_bytes + 2 * part_bytes) {
    __bf16* featb = (__bf16*)d_ws;
    __bf16* inb   = (__bf16*)((char*)d_ws + featb_bytes);
    float*  ppos  = (float*)((char*)d_ws + featb_bytes + inb_bytes);
    float*  pneg  = ppos + (size_t)GRID * NBATCH;
    cast_bf16<<<2048, 256, 0, stream>>>(inputs, features, inb, featb, out);
    triplet_main<<<GRID, 512, 0, stream>>>(inb, featb, targets, flabels, idx, ppos, pneg);
    triplet_reduce<<<NBATCH, 256, 0, stream>>>(ppos, pneg, out, GRID);
  } else {
    float* ppos = (float*)d_ws;                       // [GRIDF][256]
    float* pneg = ppos + (size_t)GRIDF * NBATCH;      // ~2.56 MB total
    triplet_partial_f32<<<GRIDF, 512, 0, stream>>>(inputs, features, targets,
                                                   flabels, idx, ppos, pneg, out);
    triplet_reduce<<<NBATCH, 256, 0, stream>>>(ppos, pneg, out, GRIDF);
  }
}